// Round 3
// baseline (1390.171 us; speedup 1.0000x reference)
//
#include <hip/hip_runtime.h>
#include <math.h>

#define EPSF 1e-5f

static constexpr int Bn   = 128;   // batch
static constexpr int Tn   = 128;   // conv time steps
static constexpr int Cn   = 32;    // conv in channels
static constexpr int On   = 2048;  // conv out channels = H*Ts
static constexpr int Hn   = 512;
static constexpr int TTn  = 512;   // total SNN steps = T*Ts
static constexpr int HORn = 96;
static constexpr int BH   = Bn * Hn;   // 65536 parallel LIF chains
static constexpr float THRf = 1.0f;

__device__ __forceinline__ float bf2f(unsigned short u) {
    union { unsigned int i; float f; } v; v.i = ((unsigned int)u) << 16; return v.f;
}
__device__ __forceinline__ unsigned short f2bf(float f) {
    union { float f; unsigned int i; } v; v.f = f;
    unsigned int r = v.i + 0x7fff + ((v.i >> 16) & 1);   // RNE
    return (unsigned short)(r >> 16);
}
struct alignas(16) us8 { unsigned short v[8]; };

// ---------------------------------------------------------------------------
// Conv1d(C=32 -> O=2048, k=3, pad=1) + bias, output written directly in
// (tt, b, h) layout where tt = t*4 + (o>>9), h = o&511.
__global__ __launch_bounds__(256) void conv_k(const float* __restrict__ x,
    const float* __restrict__ wconv, const float* __restrict__ bias,
    float* __restrict__ raw)
{
    __shared__ float xs[34][33];    // rows r -> global t = t0 + r - 1 (padded)
    __shared__ float wst[96][68];   // [ck][o_local]
    const int o0 = blockIdx.x * 64;
    const int t0 = blockIdx.y * 32;
    const int b  = blockIdx.z;
    const int tid = threadIdx.x;

    for (int i = tid; i < 64 * 96; i += 256) {
        int ol = i / 96, ck = i - ol * 96;
        wst[ck][ol] = wconv[(size_t)(o0 + ol) * 96 + ck];
    }
    for (int i = tid; i < 34 * 32; i += 256) {
        int r = i >> 5, c = i & 31;
        int tg = t0 + r - 1;
        xs[r][c] = (tg >= 0 && tg < Tn) ? x[((size_t)b * Tn + tg) * Cn + c] : 0.f;
    }
    __syncthreads();

    const int i_t = tid & 15, i_o = tid >> 4;
    const int tl = i_t * 2, ol = i_o * 4;
    float acc0[4] = {0.f, 0.f, 0.f, 0.f};
    float acc1[4] = {0.f, 0.f, 0.f, 0.f};
    for (int c = 0; c < 32; c++) {
#pragma unroll
        for (int k = 0; k < 3; k++) {
            float x0 = xs[tl + k][c];
            float x1 = xs[tl + 1 + k][c];
            const float4 wv = *(const float4*)&wst[c * 3 + k][ol];
            acc0[0] += x0 * wv.x; acc0[1] += x0 * wv.y;
            acc0[2] += x0 * wv.z; acc0[3] += x0 * wv.w;
            acc1[0] += x1 * wv.x; acc1[1] += x1 * wv.y;
            acc1[2] += x1 * wv.z; acc1[3] += x1 * wv.w;
        }
    }
#pragma unroll
    for (int i = 0; i < 2; i++) {
        int t = t0 + tl + i;
        const float* accp = i ? acc1 : acc0;
#pragma unroll
        for (int j = 0; j < 4; j++) {
            int o = o0 + ol + j;
            int ts = o >> 9, hh = o & 511;
            raw[((size_t)(t * 4 + ts) * Bn + b) * Hn + hh] = accp[j] + bias[o];
        }
    }
}

// ---------------------------------------------------------------------------
__global__ __launch_bounds__(256) void bn1_stats_k(const float* __restrict__ raw,
                                                   float* __restrict__ sums)
{
    const int hb = blockIdx.x * 32;
    const int ts = blockIdx.y;
    const int tc = blockIdx.z;          // covers t = tc*4 .. tc*4+3
    const int lane_h = threadIdx.x & 31;
    const int row = threadIdx.x >> 5;   // 0..7
    const int hh = hb + lane_h;
    float s = 0.f, ss = 0.f;
    for (int i = row; i < 512; i += 8) {
        int t = tc * 4 + (i >> 7);
        int b = i & 127;
        float v = raw[((size_t)(t * 4 + ts) * Bn + b) * Hn + hh];
        s += v; ss += v * v;
    }
    __shared__ float ls[8][33], lss[8][33];
    ls[row][lane_h] = s; lss[row][lane_h] = ss;
    __syncthreads();
    if (row == 0) {
#pragma unroll
        for (int r2 = 1; r2 < 8; r2++) { s += ls[r2][lane_h]; ss += lss[r2][lane_h]; }
        int o = ts * Hn + hh;
        atomicAdd(&sums[o], s);
        atomicAdd(&sums[On + o], ss);
    }
}

__global__ void bn1_final_k(const float* __restrict__ sums,
                            const float* __restrict__ g, const float* __restrict__ bb,
                            float* __restrict__ scale, float* __restrict__ shift)
{
    int o = blockIdx.x * 256 + threadIdx.x;   // 2048
    float m = sums[o] * (1.f / 16384.f);
    float v = sums[On + o] * (1.f / 16384.f) - m * m;
    float sc = g[o] / sqrtf(v + EPSF);
    scale[o] = sc;
    shift[o] = bb[o] - m * sc;
}

// ---------------------------------------------------------------------------
__global__ __launch_bounds__(256) void lif1_k(const float* __restrict__ raw,
    const float* __restrict__ scale, const float* __restrict__ shift,
    const float* __restrict__ beta_in, unsigned char* __restrict__ spk)
{
    const int thr = blockIdx.x * 256 + threadIdx.x;
    const int hh = thr & 511;
    const float beta = fminf(fmaxf(beta_in[hh], 0.f), 0.99f);
    float sc[4], sh[4];
#pragma unroll
    for (int ts = 0; ts < 4; ts++) { sc[ts] = scale[ts * Hn + hh]; sh[ts] = shift[ts * Hn + hh]; }
    float mem = 0.f;
    for (int tt = 0; tt < TTn; tt += 8) {
        float cu[8];
#pragma unroll
        for (int u = 0; u < 8; u++) cu[u] = raw[(size_t)(tt + u) * BH + thr];
#pragma unroll
        for (int u = 0; u < 8; u++) {
            float cur = cu[u] * sc[u & 3] + sh[u & 3];
            float reset = mem > THRf ? 1.f : 0.f;
            mem = beta * mem + cur - reset;
            spk[(size_t)(tt + u) * BH + thr] = mem > THRf ? (unsigned char)1 : (unsigned char)0;
        }
    }
}

// ---------------------------------------------------------------------------
__global__ __launch_bounds__(256) void bnstep_k(const unsigned char* __restrict__ spk,
    const float* __restrict__ g, const float* __restrict__ bb,
    float* __restrict__ av, float* __restrict__ zv)
{
    const int tt = blockIdx.x;
    const int h0 = threadIdx.x * 2;
    int c0 = 0, c1 = 0;
    const unsigned char* base = spk + (size_t)tt * BH + h0;
#pragma unroll 8
    for (int b = 0; b < Bn; b++) {
        unsigned short v = *(const unsigned short*)(base + (size_t)b * Hn);
        c0 += (v & 0xff); c1 += (v >> 8);
    }
#pragma unroll
    for (int q = 0; q < 2; q++) {
        int hh = h0 + q;
        float p = (q ? c1 : c0) * (1.f / 128.f);
        float inv = 1.f / sqrtf(p - p * p + EPSF);   // biased var = p(1-p)
        float gi = g[hh] * inv;
        float zz = bb[hh] - p * gi;
        av[(size_t)tt * Hn + hh] = gi + zz;          // value when spk=1
        zv[(size_t)tt * Hn + hh] = zz;               // value when spk=0
    }
}

__global__ __launch_bounds__(256) void lif2_k(const unsigned char* __restrict__ sin_,
    const float* __restrict__ av, const float* __restrict__ zv,
    const float* __restrict__ beta_in, unsigned char* __restrict__ sout)
{
    const int thr = blockIdx.x * 256 + threadIdx.x;
    const int hh = thr & 511;
    const float beta = fminf(fmaxf(beta_in[hh], 0.f), 0.99f);
    float mem = 0.f;
    for (int tt = 0; tt < TTn; tt += 8) {
        float aa[8], zz[8]; unsigned char ss[8];
#pragma unroll
        for (int u = 0; u < 8; u++) {
            ss[u] = sin_[(size_t)(tt + u) * BH + thr];
            aa[u] = av[(size_t)(tt + u) * Hn + hh];
            zz[u] = zv[(size_t)(tt + u) * Hn + hh];
        }
#pragma unroll
        for (int u = 0; u < 8; u++) {
            float cur = ss[u] ? aa[u] : zz[u];
            float reset = mem > THRf ? 1.f : 0.f;
            mem = beta * mem + cur - reset;
            sout[(size_t)(tt + u) * BH + thr] = mem > THRf ? (unsigned char)1 : (unsigned char)0;
        }
    }
}

// LIF3: emits post-update membrane in (b, tt, h) layout.
__global__ __launch_bounds__(256) void lif3_k(const unsigned char* __restrict__ sin_,
    const float* __restrict__ av, const float* __restrict__ zv,
    const float* __restrict__ beta_in, float* __restrict__ mem3)
{
    const int thr = blockIdx.x * 256 + threadIdx.x;
    const int hh = thr & 511;
    const int b = thr >> 9;
    const float beta = fminf(fmaxf(beta_in[hh], 0.f), 0.99f);
    float mem = 0.f;
    for (int tt = 0; tt < TTn; tt += 8) {
        float aa[8], zz[8]; unsigned char ss[8];
#pragma unroll
        for (int u = 0; u < 8; u++) {
            ss[u] = sin_[(size_t)(tt + u) * BH + thr];
            aa[u] = av[(size_t)(tt + u) * Hn + hh];
            zz[u] = zv[(size_t)(tt + u) * Hn + hh];
        }
#pragma unroll
        for (int u = 0; u < 8; u++) {
            float cur = ss[u] ? aa[u] : zz[u];
            float reset = mem > THRf ? 1.f : 0.f;
            mem = beta * mem + cur - reset;
            mem3[((size_t)b * TTn + (tt + u)) * Hn + hh] = mem;
        }
    }
}

// ---------------------------------------------------------------------------
// G[d,e] = sum_i wq[i,d] * wk[i,e]   (A^T B, both 512x512 row-major)
__global__ __launch_bounds__(256) void gemm_atb_k(const float* __restrict__ Aw,
    const float* __restrict__ Bw, float* __restrict__ C)
{
    __shared__ float As[8][132];
    __shared__ float Bs[8][132];
    const int m0 = blockIdx.x * 128;
    const int n0 = blockIdx.y * 128;
    const int tid = threadIdx.x;
    const int ir = tid >> 5, cl = (tid & 31) * 4;
    const float* Ap = Aw + (size_t)ir * 512 + m0 + cl;
    const float* Bp = Bw + (size_t)ir * 512 + n0 + cl;
    const int tm = tid & 15, tn = tid >> 4;
    float acc[8][8];
#pragma unroll
    for (int i = 0; i < 8; i++)
#pragma unroll
        for (int j = 0; j < 8; j++) acc[i][j] = 0.f;

    for (int i0 = 0; i0 < 512; i0 += 8) {
        const float4 avv = *(const float4*)(Ap + (size_t)i0 * 512);
        const float4 bvv = *(const float4*)(Bp + (size_t)i0 * 512);
        __syncthreads();
        *(float4*)&As[ir][cl] = avv;
        *(float4*)&Bs[ir][cl] = bvv;
        __syncthreads();
#pragma unroll
        for (int kk = 0; kk < 8; kk++) {
            float4 a0 = *(const float4*)&As[kk][tm * 8];
            float4 a1 = *(const float4*)&As[kk][tm * 8 + 4];
            float4 b0 = *(const float4*)&Bs[kk][tn * 8];
            float4 b1 = *(const float4*)&Bs[kk][tn * 8 + 4];
            float a_[8] = {a0.x, a0.y, a0.z, a0.w, a1.x, a1.y, a1.z, a1.w};
            float b_[8] = {b0.x, b0.y, b0.z, b0.w, b1.x, b1.y, b1.z, b1.w};
#pragma unroll
            for (int i = 0; i < 8; i++)
#pragma unroll
                for (int j = 0; j < 8; j++) acc[i][j] += a_[i] * b_[j];
        }
    }
#pragma unroll
    for (int i = 0; i < 8; i++) {
        size_t rowoff = (size_t)(m0 + tm * 8 + i) * 512 + n0 + tn * 8;
#pragma unroll
        for (int j = 0; j < 8; j++) C[rowoff + j] = acc[i][j];
    }
}

// qb[d] = sum_i wq[i,d]*bk[i]; kb[d] = sum_i wk[i,d]*bq[i]; c0 = bq.bk
__global__ __launch_bounds__(256) void bias_prep_k(const float* __restrict__ wq,
    const float* __restrict__ wk, const float* __restrict__ bq,
    const float* __restrict__ bk, float* __restrict__ qb, float* __restrict__ kb,
    float* __restrict__ c0)
{
    const int d = blockIdx.x * 256 + threadIdx.x;
    float sq = 0.f, sk = 0.f;
    for (int i = 0; i < 512; i++) {
        sq += wq[(size_t)i * 512 + d] * bk[i];
        sk += wk[(size_t)i * 512 + d] * bq[i];
    }
    qb[d] = sq; kb[d] = sk;
    if (blockIdx.x == 0) {
        __shared__ float red[256];
        float p = 0.f;
        for (int i = threadIdx.x; i < 512; i += 256) p += bq[i] * bk[i];
        red[threadIdx.x] = p;
        __syncthreads();
        for (int s = 128; s > 0; s >>= 1) {
            if (threadIdx.x < s) red[threadIdx.x] += red[threadIdx.x + s];
            __syncthreads();
        }
        if (threadIdx.x == 0) c0[0] = red[0];
    }
}

// Y = mem3 @ G   (M=65536, N=K=512), output stored as bf16.
__global__ __launch_bounds__(256) void gemm_nn_k(const float* __restrict__ A,
    const float* __restrict__ B, unsigned short* __restrict__ C)
{
    __shared__ float As[8][132];
    __shared__ float Bs[8][132];
    const int m0 = blockIdx.x * 128;
    const int n0 = blockIdx.y * 128;
    const int tid = threadIdx.x;
    const int lr = tid >> 1, lk = (tid & 1) * 4;
    const int kr = tid >> 5, nl = (tid & 31) * 4;
    const float* Ap = A + (size_t)(m0 + lr) * 512 + lk;
    const float* Bp = B + (size_t)kr * 512 + n0 + nl;
    const int tm = tid & 15, tn = tid >> 4;
    float acc[8][8];
#pragma unroll
    for (int i = 0; i < 8; i++)
#pragma unroll
        for (int j = 0; j < 8; j++) acc[i][j] = 0.f;

    for (int k0 = 0; k0 < 512; k0 += 8) {
        const float4 avv = *(const float4*)(Ap + k0);
        const float4 bvv = *(const float4*)(Bp + (size_t)k0 * 512);
        __syncthreads();
        As[lk + 0][lr] = avv.x; As[lk + 1][lr] = avv.y;
        As[lk + 2][lr] = avv.z; As[lk + 3][lr] = avv.w;
        *(float4*)&Bs[kr][nl] = bvv;
        __syncthreads();
#pragma unroll
        for (int kk = 0; kk < 8; kk++) {
            float4 a0 = *(const float4*)&As[kk][tm * 8];
            float4 a1 = *(const float4*)&As[kk][tm * 8 + 4];
            float4 b0 = *(const float4*)&Bs[kk][tn * 8];
            float4 b1 = *(const float4*)&Bs[kk][tn * 8 + 4];
            float a_[8] = {a0.x, a0.y, a0.z, a0.w, a1.x, a1.y, a1.z, a1.w};
            float b_[8] = {b0.x, b0.y, b0.z, b0.w, b1.x, b1.y, b1.z, b1.w};
#pragma unroll
            for (int i = 0; i < 8; i++)
#pragma unroll
                for (int j = 0; j < 8; j++) acc[i][j] += a_[i] * b_[j];
        }
    }
#pragma unroll
    for (int i = 0; i < 8; i++) {
        size_t rowoff = (size_t)(m0 + tm * 8 + i) * 512 + n0 + tn * 8;
        us8 o8;
#pragma unroll
        for (int j = 0; j < 8; j++) o8.v[j] = f2bf(acc[i][j]);
        *(us8*)&C[rowoff] = o8;
    }
}

// rowq[r] = mem3[r,:].qb + c0 ; rowk[r] = mem3[r,:].kb   (r = b*512+tt)
__global__ __launch_bounds__(256) void rows_k(const float* __restrict__ mem3,
    const float* __restrict__ qb, const float* __restrict__ kb,
    const float* __restrict__ c0, float* __restrict__ rowq, float* __restrict__ rowk)
{
    const int wave = threadIdx.x >> 6;
    const int lane = threadIdx.x & 63;
    const int row = blockIdx.x * 4 + wave;
    const float* xr = mem3 + (size_t)row * 512 + lane * 8;
    const float4 x0 = *(const float4*)xr;
    const float4 x1 = *(const float4*)(xr + 4);
    const float4 q0 = *(const float4*)(qb + lane * 8);
    const float4 q1 = *(const float4*)(qb + lane * 8 + 4);
    const float4 k0 = *(const float4*)(kb + lane * 8);
    const float4 k1 = *(const float4*)(kb + lane * 8 + 4);
    float sq = x0.x*q0.x + x0.y*q0.y + x0.z*q0.z + x0.w*q0.w
             + x1.x*q1.x + x1.y*q1.y + x1.z*q1.z + x1.w*q1.w;
    float sk = x0.x*k0.x + x0.y*k0.y + x0.z*k0.z + x0.w*k0.w
             + x1.x*k1.x + x1.y*k1.y + x1.z*k1.z + x1.w*k1.w;
#pragma unroll
    for (int off = 32; off > 0; off >>= 1) {
        sq += __shfl_down(sq, off);
        sk += __shfl_down(sk, off);
    }
    if (lane == 0) {
        rowq[row] = sq + c0[0];
        rowk[row] = sk;
    }
}

// ---------------------------------------------------------------------------
// wacc[b,s] += (1/512) * sum_t sigmoid((Y X^T + rowq_t + rowk_s) / sqrt(H))
// Y is bf16, X (mem3) fp32.
__global__ __launch_bounds__(256) void scores_k(const unsigned short* __restrict__ Y,
    const float* __restrict__ Xm, const float* __restrict__ rowq,
    const float* __restrict__ rowk, float* __restrict__ wacc)
{
    __shared__ float As[8][132];
    __shared__ float Bs[8][132];
    __shared__ float colsum[128];
    const int b = blockIdx.z;
    const int m0 = blockIdx.x * 128;   // t tile
    const int n0 = blockIdx.y * 128;   // s tile
    const unsigned short* A = Y + (size_t)b * TTn * Hn;
    const float* Bm = Xm + (size_t)b * TTn * Hn;
    const int tid = threadIdx.x;
    const int lr = tid >> 1;
    const int lk = (tid & 1) * 4;
    const unsigned short* Ap = A + (size_t)(m0 + lr) * 512 + lk;
    const float* Bp = Bm + (size_t)(n0 + lr) * 512 + lk;
    const int tm = tid & 15, tn = tid >> 4;
    if (tid < 128) colsum[tid] = 0.f;
    float acc[8][8];
#pragma unroll
    for (int i = 0; i < 8; i++)
#pragma unroll
        for (int j = 0; j < 8; j++) acc[i][j] = 0.f;

    for (int k0 = 0; k0 < 512; k0 += 8) {
        const ushort4 avv = *(const ushort4*)(Ap + k0);
        const float4 bvv = *(const float4*)(Bp + k0);
        __syncthreads();
        As[lk + 0][lr] = bf2f(avv.x); As[lk + 1][lr] = bf2f(avv.y);
        As[lk + 2][lr] = bf2f(avv.z); As[lk + 3][lr] = bf2f(avv.w);
        Bs[lk + 0][lr] = bvv.x; Bs[lk + 1][lr] = bvv.y;
        Bs[lk + 2][lr] = bvv.z; Bs[lk + 3][lr] = bvv.w;
        __syncthreads();
#pragma unroll
        for (int kk = 0; kk < 8; kk++) {
            float4 a0 = *(const float4*)&As[kk][tm * 8];
            float4 a1 = *(const float4*)&As[kk][tm * 8 + 4];
            float4 b0 = *(const float4*)&Bs[kk][tn * 8];
            float4 b1 = *(const float4*)&Bs[kk][tn * 8 + 4];
            float a_[8] = {a0.x, a0.y, a0.z, a0.w, a1.x, a1.y, a1.z, a1.w};
            float b_[8] = {b0.x, b0.y, b0.z, b0.w, b1.x, b1.y, b1.z, b1.w};
#pragma unroll
            for (int i = 0; i < 8; i++)
#pragma unroll
                for (int j = 0; j < 8; j++) acc[i][j] += a_[i] * b_[j];
        }
    }
    float rq[8], rk[8];
#pragma unroll
    for (int i = 0; i < 8; i++) rq[i] = rowq[(size_t)b * TTn + m0 + tm * 8 + i];
#pragma unroll
    for (int j = 0; j < 8; j++) rk[j] = rowk[(size_t)b * TTn + n0 + tn * 8 + j];
    const float scl = 0.044194173824159216f;   // 512^-0.5
#pragma unroll
    for (int j = 0; j < 8; j++) {
        float s = 0.f;
#pragma unroll
        for (int i = 0; i < 8; i++) {
            float xv = (acc[i][j] + rq[i] + rk[j]) * scl;
            s += 1.f / (1.f + __expf(-xv));
        }
        atomicAdd(&colsum[tn * 8 + j], s);
    }
    __syncthreads();
    if (tid < 128)
        atomicAdd(&wacc[(size_t)b * TTn + n0 + tid], colsum[tid] * (1.f / 512.f));
}

// u[b,e] = sum_s wacc[b,s]*mem3[b,s,e];  W1[b] = sum_s wacc[b,s]
__global__ __launch_bounds__(256) void wsum_k(const float* __restrict__ wacc,
    const float* __restrict__ mem3, float* __restrict__ u, float* __restrict__ W1)
{
    const int b = blockIdx.x;
    const int tid = threadIdx.x;
    __shared__ float ws_[512];
    __shared__ float red[256];
    ws_[tid] = wacc[(size_t)b * TTn + tid];
    ws_[tid + 256] = wacc[(size_t)b * TTn + tid + 256];
    __syncthreads();
    red[tid] = ws_[tid] + ws_[tid + 256];
    __syncthreads();
    for (int s = 128; s > 0; s >>= 1) {
        if (tid < s) red[tid] += red[tid + s];
        __syncthreads();
    }
    if (tid == 0) W1[b] = red[0];
    float a0 = 0.f, a1 = 0.f;
    const float* Xb = mem3 + (size_t)b * TTn * Hn;
    for (int s = 0; s < TTn; s++) {
        float w = ws_[s];
        a0 += w * Xb[(size_t)s * Hn + tid];
        a1 += w * Xb[(size_t)s * Hn + tid + 256];
    }
    u[(size_t)b * Hn + tid] = a0;
    u[(size_t)b * Hn + tid + 256] = a1;
}

// feat[b,d] = u[b,:].wv[d,:] + bv[d]*W1[b]
__global__ __launch_bounds__(256) void feat2_k(const float* __restrict__ u,
    const float* __restrict__ W1, const float* __restrict__ wv,
    const float* __restrict__ bv, float* __restrict__ feat)
{
    const int b = blockIdx.x;
    const int tid = threadIdx.x;
    __shared__ float us[512];
    us[tid] = u[(size_t)b * Hn + tid];
    us[tid + 256] = u[(size_t)b * Hn + tid + 256];
    __syncthreads();
    const float w1 = W1[b];
#pragma unroll
    for (int q = 0; q < 2; q++) {
        int d = tid + q * 256;
        float acc = bv[d] * w1;
        const float* wr = wv + (size_t)d * 512;
        for (int e = 0; e < 512; e += 4) {
            float4 w4 = *(const float4*)(wr + e);
            acc += us[e] * w4.x + us[e+1] * w4.y + us[e+2] * w4.z + us[e+3] * w4.w;
        }
        feat[(size_t)b * Hn + d] = acc;
    }
}

// BatchNorm over batch per feature d (biased var).
__global__ void bna_k(const float* __restrict__ feat, const float* __restrict__ g,
                      const float* __restrict__ bb, float* __restrict__ featn)
{
    int d = blockIdx.x * 256 + threadIdx.x;   // 512 total
    float s = 0.f, ss = 0.f;
    for (int b = 0; b < Bn; b++) { float v = feat[(size_t)b * Hn + d]; s += v; ss += v * v; }
    float m = s * (1.f / 128.f);
    float var = ss * (1.f / 128.f) - m * m;
    float sc = g[d] / sqrtf(var + EPSF);
    float sh = bb[d] - m * sc;
    for (int b = 0; b < Bn; b++) featn[(size_t)b * Hn + d] = feat[(size_t)b * Hn + d] * sc + sh;
}

__global__ __launch_bounds__(128) void head_k(const float* __restrict__ featn,
    const float* __restrict__ wh, const float* __restrict__ bh, float* __restrict__ out)
{
    const int b = blockIdx.x;
    __shared__ float f[512];
    const int tid = threadIdx.x;
    for (int i = tid; i < 512; i += 128) f[i] = featn[(size_t)b * Hn + i];
    __syncthreads();
    if (tid < HORn) {
        float accv = bh[tid];
        const float* wr = wh + (size_t)tid * Hn;
        for (int d = 0; d < 512; d++) accv += f[d] * wr[d];
        out[(size_t)b * HORn + tid] = accv;
    }
}

// Diagnostic: if workspace is too small, encode ws_size in out[0].
__global__ void dbg_k(float* out, float v) { out[0] = v; }

// ---------------------------------------------------------------------------
extern "C" void kernel_launch(void* const* d_in, const int* in_sizes, int n_in,
                              void* d_out, int out_size, void* d_ws, size_t ws_size,
                              hipStream_t stream)
{
    (void)in_sizes; (void)n_in;
    const float* x      = (const float*)d_in[0];
    const float* conv_w = (const float*)d_in[1];
    const float* conv_b = (const float*)d_in[2];
    const float* bn1_g  = (const float*)d_in[3];
    const float* bn1_b  = (const float*)d_in[4];
    const float* beta_e = (const float*)d_in[5];
    const float* bn2_g  = (const float*)d_in[6];
    const float* bn2_b  = (const float*)d_in[7];
    const float* beta2  = (const float*)d_in[8];
    const float* bn3_g  = (const float*)d_in[9];
    const float* bn3_b  = (const float*)d_in[10];
    const float* beta3  = (const float*)d_in[11];
    const float* wq     = (const float*)d_in[12];
    const float* bq     = (const float*)d_in[13];
    const float* wk     = (const float*)d_in[14];
    const float* bk     = (const float*)d_in[15];
    const float* wv     = (const float*)d_in[16];
    const float* bv     = (const float*)d_in[17];
    const float* bna_g  = (const float*)d_in[18];
    const float* bna_b  = (const float*)d_in[19];
    const float* wh     = (const float*)d_in[20];
    const float* bh     = (const float*)d_in[21];
    float* out = (float*)d_out;

    char* ws = (char*)d_ws;
    size_t off = 0;
    auto alloc = [&](size_t bytes) {
        char* p = ws + off;
        off += (bytes + 255) & ~(size_t)255;
        return p;
    };
    // Big region 1: raw (fp32, 134 MB), aliased by mem3 after lif1.
    float* raw          = (float*)alloc((size_t)TTn * Bn * Hn * 4);
    // Big region 2: spk1 + s2 (67 MB total), aliased by Y (bf16, 67 MB) after lif3.
    unsigned char* spk1 = (unsigned char*)alloc((size_t)TTn * BH);
    unsigned char* s2   = (unsigned char*)alloc((size_t)TTn * BH);
    float* sums   = (float*)alloc(2 * On * 4);
    float* scale1 = (float*)alloc(On * 4);
    float* shift1 = (float*)alloc(On * 4);
    float* a2     = (float*)alloc((size_t)TTn * Hn * 4);
    float* z2     = (float*)alloc((size_t)TTn * Hn * 4);
    float* a3     = (float*)alloc((size_t)TTn * Hn * 4);
    float* z3     = (float*)alloc((size_t)TTn * Hn * 4);
    float* wacc   = (float*)alloc((size_t)Bn * TTn * 4);
    float* G      = (float*)alloc((size_t)Hn * Hn * 4);
    float* qb     = (float*)alloc(Hn * 4);
    float* kb     = (float*)alloc(Hn * 4);
    float* c0     = (float*)alloc(256);
    float* rowq   = (float*)alloc((size_t)Bn * TTn * 4);
    float* rowk   = (float*)alloc((size_t)Bn * TTn * 4);
    float* u      = (float*)alloc((size_t)Bn * Hn * 4);
    float* W1     = (float*)alloc(Bn * 4);
    float* feat   = (float*)alloc((size_t)Bn * Hn * 4);
    float* featn  = (float*)alloc((size_t)Bn * Hn * 4);
    float* mem3 = raw;                       // raw dead after lif1
    unsigned short* Y = (unsigned short*)spk1;  // spikes dead after lif3; bf16 Y = 67 MB fits spk1+s2

    if (ws_size < off) {
        hipMemsetAsync(d_out, 0, (size_t)out_size * 4, stream);
        dbg_k<<<1, 1, 0, stream>>>(out, (float)ws_size);
        return;
    }

    hipMemsetAsync(sums, 0, 2 * On * 4, stream);
    hipMemsetAsync(wacc, 0, (size_t)Bn * TTn * 4, stream);

    conv_k<<<dim3(On / 64, Tn / 32, Bn), 256, 0, stream>>>(x, conv_w, conv_b, raw);
    bn1_stats_k<<<dim3(16, 4, 32), 256, 0, stream>>>(raw, sums);
    bn1_final_k<<<On / 256, 256, 0, stream>>>(sums, bn1_g, bn1_b, scale1, shift1);
    lif1_k<<<BH / 256, 256, 0, stream>>>(raw, scale1, shift1, beta_e, spk1);
    bnstep_k<<<TTn, 256, 0, stream>>>(spk1, bn2_g, bn2_b, a2, z2);
    lif2_k<<<BH / 256, 256, 0, stream>>>(spk1, a2, z2, beta2, s2);
    bnstep_k<<<TTn, 256, 0, stream>>>(s2, bn3_g, bn3_b, a3, z3);
    lif3_k<<<BH / 256, 256, 0, stream>>>(s2, a3, z3, beta3, mem3);
    gemm_atb_k<<<dim3(4, 4), 256, 0, stream>>>(wq, wk, G);
    bias_prep_k<<<2, 256, 0, stream>>>(wq, wk, bq, bk, qb, kb, c0);
    gemm_nn_k<<<dim3((Bn * TTn) / 128, Hn / 128), 256, 0, stream>>>(mem3, G, Y);
    rows_k<<<(Bn * TTn) / 4, 256, 0, stream>>>(mem3, qb, kb, c0, rowq, rowk);
    scores_k<<<dim3(TTn / 128, TTn / 128, Bn), 256, 0, stream>>>(Y, mem3, rowq, rowk, wacc);
    wsum_k<<<Bn, 256, 0, stream>>>(wacc, mem3, u, W1);
    feat2_k<<<Bn, 256, 0, stream>>>(u, W1, wv, bv, feat);
    bna_k<<<Hn / 256, 256, 0, stream>>>(feat, bna_g, bna_b, featn);
    head_k<<<Bn, 128, 0, stream>>>(featn, wh, bh, out);
}

// Round 4
// 738.895 us; speedup vs baseline: 1.8814x; 1.8814x over previous
//
#include <hip/hip_runtime.h>
#include <math.h>

#define EPSF 1e-5f

static constexpr int Bn   = 128;   // batch
static constexpr int Tn   = 128;   // conv time steps
static constexpr int Cn   = 32;    // conv in channels
static constexpr int On   = 2048;  // conv out channels = H*Ts
static constexpr int Hn   = 512;
static constexpr int TTn  = 512;   // total SNN steps = T*Ts
static constexpr int HORn = 96;
static constexpr int BH   = Bn * Hn;   // 65536 parallel LIF chains
static constexpr float THRf = 1.0f;

__device__ __forceinline__ float bf2f(unsigned short u) {
    union { unsigned int i; float f; } v; v.i = ((unsigned int)u) << 16; return v.f;
}
__device__ __forceinline__ unsigned short f2bf(float f) {
    union { float f; unsigned int i; } v; v.f = f;
    unsigned int r = v.i + 0x7fff + ((v.i >> 16) & 1);   // RNE
    return (unsigned short)(r >> 16);
}

using bfrag  = __attribute__((ext_vector_type(8))) short;   // 8 bf16 = 4 VGPRs
using f32x4v = __attribute__((ext_vector_type(4))) float;   // MFMA C/D
using us8v   = __attribute__((ext_vector_type(8))) unsigned short;

// ---------------------------------------------------------------------------
// Conv1d(C=32 -> O=2048, k=3, pad=1) + bias -> (tt, b, h) fp32.
__global__ __launch_bounds__(256) void conv_k(const float* __restrict__ x,
    const float* __restrict__ wconv, const float* __restrict__ bias,
    float* __restrict__ raw)
{
    __shared__ float xs[34][33];
    __shared__ float wst[96][68];
    const int o0 = blockIdx.x * 64;
    const int t0 = blockIdx.y * 32;
    const int b  = blockIdx.z;
    const int tid = threadIdx.x;

    for (int i = tid; i < 64 * 96; i += 256) {
        int ol = i / 96, ck = i - ol * 96;
        wst[ck][ol] = wconv[(size_t)(o0 + ol) * 96 + ck];
    }
    for (int i = tid; i < 34 * 32; i += 256) {
        int r = i >> 5, c = i & 31;
        int tg = t0 + r - 1;
        xs[r][c] = (tg >= 0 && tg < Tn) ? x[((size_t)b * Tn + tg) * Cn + c] : 0.f;
    }
    __syncthreads();

    const int i_t = tid & 15, i_o = tid >> 4;
    const int tl = i_t * 2, ol = i_o * 4;
    float acc0[4] = {0.f, 0.f, 0.f, 0.f};
    float acc1[4] = {0.f, 0.f, 0.f, 0.f};
    for (int c = 0; c < 32; c++) {
#pragma unroll
        for (int k = 0; k < 3; k++) {
            float x0 = xs[tl + k][c];
            float x1 = xs[tl + 1 + k][c];
            const float4 wv = *(const float4*)&wst[c * 3 + k][ol];
            acc0[0] += x0 * wv.x; acc0[1] += x0 * wv.y;
            acc0[2] += x0 * wv.z; acc0[3] += x0 * wv.w;
            acc1[0] += x1 * wv.x; acc1[1] += x1 * wv.y;
            acc1[2] += x1 * wv.z; acc1[3] += x1 * wv.w;
        }
    }
#pragma unroll
    for (int i = 0; i < 2; i++) {
        int t = t0 + tl + i;
        const float* accp = i ? acc1 : acc0;
#pragma unroll
        for (int j = 0; j < 4; j++) {
            int o = o0 + ol + j;
            int ts = o >> 9, hh = o & 511;
            raw[((size_t)(t * 4 + ts) * Bn + b) * Hn + hh] = accp[j] + bias[o];
        }
    }
}

// ---------------------------------------------------------------------------
__global__ __launch_bounds__(256) void bn1_stats_k(const float* __restrict__ raw,
                                                   float* __restrict__ sums)
{
    const int hb = blockIdx.x * 32;
    const int ts = blockIdx.y;
    const int tc = blockIdx.z;
    const int lane_h = threadIdx.x & 31;
    const int row = threadIdx.x >> 5;
    const int hh = hb + lane_h;
    float s = 0.f, ss = 0.f;
    for (int i = row; i < 512; i += 8) {
        int t = tc * 4 + (i >> 7);
        int b = i & 127;
        float v = raw[((size_t)(t * 4 + ts) * Bn + b) * Hn + hh];
        s += v; ss += v * v;
    }
    __shared__ float ls[8][33], lss[8][33];
    ls[row][lane_h] = s; lss[row][lane_h] = ss;
    __syncthreads();
    if (row == 0) {
#pragma unroll
        for (int r2 = 1; r2 < 8; r2++) { s += ls[r2][lane_h]; ss += lss[r2][lane_h]; }
        int o = ts * Hn + hh;
        atomicAdd(&sums[o], s);
        atomicAdd(&sums[On + o], ss);
    }
}

__global__ void bn1_final_k(const float* __restrict__ sums,
                            const float* __restrict__ g, const float* __restrict__ bb,
                            float* __restrict__ scale, float* __restrict__ shift)
{
    int o = blockIdx.x * 256 + threadIdx.x;
    float m = sums[o] * (1.f / 16384.f);
    float v = sums[On + o] * (1.f / 16384.f) - m * m;
    float sc = g[o] / sqrtf(v + EPSF);
    scale[o] = sc;
    shift[o] = bb[o] - m * sc;
}

// ---------------------------------------------------------------------------
__global__ __launch_bounds__(256) void lif1_k(const float* __restrict__ raw,
    const float* __restrict__ scale, const float* __restrict__ shift,
    const float* __restrict__ beta_in, unsigned char* __restrict__ spk)
{
    const int thr = blockIdx.x * 256 + threadIdx.x;
    const int hh = thr & 511;
    const float beta = fminf(fmaxf(beta_in[hh], 0.f), 0.99f);
    float sc[4], sh[4];
#pragma unroll
    for (int ts = 0; ts < 4; ts++) { sc[ts] = scale[ts * Hn + hh]; sh[ts] = shift[ts * Hn + hh]; }
    float mem = 0.f;
    for (int tt = 0; tt < TTn; tt += 8) {
        float cu[8];
#pragma unroll
        for (int u = 0; u < 8; u++) cu[u] = raw[(size_t)(tt + u) * BH + thr];
#pragma unroll
        for (int u = 0; u < 8; u++) {
            float cur = cu[u] * sc[u & 3] + sh[u & 3];
            float reset = mem > THRf ? 1.f : 0.f;
            mem = beta * mem + cur - reset;
            spk[(size_t)(tt + u) * BH + thr] = mem > THRf ? (unsigned char)1 : (unsigned char)0;
        }
    }
}

// ---------------------------------------------------------------------------
__global__ __launch_bounds__(256) void bnstep_k(const unsigned char* __restrict__ spk,
    const float* __restrict__ g, const float* __restrict__ bb,
    float* __restrict__ av, float* __restrict__ zv)
{
    const int tt = blockIdx.x;
    const int h0 = threadIdx.x * 2;
    int c0 = 0, c1 = 0;
    const unsigned char* base = spk + (size_t)tt * BH + h0;
#pragma unroll 8
    for (int b = 0; b < Bn; b++) {
        unsigned short v = *(const unsigned short*)(base + (size_t)b * Hn);
        c0 += (v & 0xff); c1 += (v >> 8);
    }
#pragma unroll
    for (int q = 0; q < 2; q++) {
        int hh = h0 + q;
        float p = (q ? c1 : c0) * (1.f / 128.f);
        float inv = 1.f / sqrtf(p - p * p + EPSF);
        float gi = g[hh] * inv;
        float zz = bb[hh] - p * gi;
        av[(size_t)tt * Hn + hh] = gi + zz;          // value when spk=1
        zv[(size_t)tt * Hn + hh] = zz;               // value when spk=0
    }
}

__global__ __launch_bounds__(256) void lif2_k(const unsigned char* __restrict__ sin_,
    const float* __restrict__ av, const float* __restrict__ zv,
    const float* __restrict__ beta_in, unsigned char* __restrict__ sout)
{
    const int thr = blockIdx.x * 256 + threadIdx.x;
    const int hh = thr & 511;
    const float beta = fminf(fmaxf(beta_in[hh], 0.f), 0.99f);
    float mem = 0.f;
    for (int tt = 0; tt < TTn; tt += 8) {
        float aa[8], zz[8]; unsigned char ss[8];
#pragma unroll
        for (int u = 0; u < 8; u++) {
            ss[u] = sin_[(size_t)(tt + u) * BH + thr];
            aa[u] = av[(size_t)(tt + u) * Hn + hh];
            zz[u] = zv[(size_t)(tt + u) * Hn + hh];
        }
#pragma unroll
        for (int u = 0; u < 8; u++) {
            float cur = ss[u] ? aa[u] : zz[u];
            float reset = mem > THRf ? 1.f : 0.f;
            mem = beta * mem + cur - reset;
            sout[(size_t)(tt + u) * BH + thr] = mem > THRf ? (unsigned char)1 : (unsigned char)0;
        }
    }
}

// LIF3: emits post-update membrane as bf16 in (b, tt, h) layout.
__global__ __launch_bounds__(256) void lif3_k(const unsigned char* __restrict__ sin_,
    const float* __restrict__ av, const float* __restrict__ zv,
    const float* __restrict__ beta_in, unsigned short* __restrict__ mem3b)
{
    const int thr = blockIdx.x * 256 + threadIdx.x;
    const int hh = thr & 511;
    const int b = thr >> 9;
    const float beta = fminf(fmaxf(beta_in[hh], 0.f), 0.99f);
    float mem = 0.f;
    for (int tt = 0; tt < TTn; tt += 8) {
        float aa[8], zz[8]; unsigned char ss[8];
#pragma unroll
        for (int u = 0; u < 8; u++) {
            ss[u] = sin_[(size_t)(tt + u) * BH + thr];
            aa[u] = av[(size_t)(tt + u) * Hn + hh];
            zz[u] = zv[(size_t)(tt + u) * Hn + hh];
        }
#pragma unroll
        for (int u = 0; u < 8; u++) {
            float cur = ss[u] ? aa[u] : zz[u];
            float reset = mem > THRf ? 1.f : 0.f;
            mem = beta * mem + cur - reset;
            mem3b[((size_t)b * TTn + (tt + u)) * Hn + hh] = f2bf(mem);
        }
    }
}

// ---------------------------------------------------------------------------
// GT[e,d] = sum_i wk[i,e] * wq[i,d]  (call as (wk, wq)) — bf16 output.
__global__ __launch_bounds__(256) void gemm_atb_k(const float* __restrict__ Aw,
    const float* __restrict__ Bw, unsigned short* __restrict__ C)
{
    __shared__ float As[8][132];
    __shared__ float Bs[8][132];
    const int m0 = blockIdx.x * 128;
    const int n0 = blockIdx.y * 128;
    const int tid = threadIdx.x;
    const int ir = tid >> 5, cl = (tid & 31) * 4;
    const float* Ap = Aw + (size_t)ir * 512 + m0 + cl;
    const float* Bp = Bw + (size_t)ir * 512 + n0 + cl;
    const int tm = tid & 15, tn = tid >> 4;
    float acc[8][8];
#pragma unroll
    for (int i = 0; i < 8; i++)
#pragma unroll
        for (int j = 0; j < 8; j++) acc[i][j] = 0.f;

    for (int i0 = 0; i0 < 512; i0 += 8) {
        const float4 avv = *(const float4*)(Ap + (size_t)i0 * 512);
        const float4 bvv = *(const float4*)(Bp + (size_t)i0 * 512);
        __syncthreads();
        *(float4*)&As[ir][cl] = avv;
        *(float4*)&Bs[ir][cl] = bvv;
        __syncthreads();
#pragma unroll
        for (int kk = 0; kk < 8; kk++) {
            float4 a0 = *(const float4*)&As[kk][tm * 8];
            float4 a1 = *(const float4*)&As[kk][tm * 8 + 4];
            float4 b0 = *(const float4*)&Bs[kk][tn * 8];
            float4 b1 = *(const float4*)&Bs[kk][tn * 8 + 4];
            float a_[8] = {a0.x, a0.y, a0.z, a0.w, a1.x, a1.y, a1.z, a1.w};
            float b_[8] = {b0.x, b0.y, b0.z, b0.w, b1.x, b1.y, b1.z, b1.w};
#pragma unroll
            for (int i = 0; i < 8; i++)
#pragma unroll
                for (int j = 0; j < 8; j++) acc[i][j] += a_[i] * b_[j];
        }
    }
#pragma unroll
    for (int i = 0; i < 8; i++) {
        size_t rowoff = (size_t)(m0 + tm * 8 + i) * 512 + n0 + tn * 8;
#pragma unroll
        for (int j = 0; j < 8; j++) C[rowoff + j] = f2bf(acc[i][j]);
    }
}

// qb[d] = sum_i wq[i,d]*bk[i]; kb[d] = sum_i wk[i,d]*bq[i]; c0 = bq.bk
__global__ __launch_bounds__(256) void bias_prep_k(const float* __restrict__ wq,
    const float* __restrict__ wk, const float* __restrict__ bq,
    const float* __restrict__ bk, float* __restrict__ qb, float* __restrict__ kb,
    float* __restrict__ c0)
{
    const int d = blockIdx.x * 256 + threadIdx.x;
    float sq = 0.f, sk = 0.f;
    for (int i = 0; i < 512; i++) {
        sq += wq[(size_t)i * 512 + d] * bk[i];
        sk += wk[(size_t)i * 512 + d] * bq[i];
    }
    qb[d] = sq; kb[d] = sk;
    if (blockIdx.x == 0) {
        __shared__ float red[256];
        float p = 0.f;
        for (int i = threadIdx.x; i < 512; i += 256) p += bq[i] * bk[i];
        red[threadIdx.x] = p;
        __syncthreads();
        for (int s = 128; s > 0; s >>= 1) {
            if (threadIdx.x < s) red[threadIdx.x] += red[threadIdx.x + s];
            __syncthreads();
        }
        if (threadIdx.x == 0) c0[0] = red[0];
    }
}

// ---------------------------------------------------------------------------
// MFMA NT GEMM: Y[r,e] = sum_d mem3b[r,d] * GT[e,d]; all bf16, fp32 acc.
// 128x128 tile, 4 waves in 2x2, each wave 64x64 = 4x4 frags of 16x16x32.
__global__ __launch_bounds__(256) void ygemm_k(const unsigned short* __restrict__ A,
    const unsigned short* __restrict__ Bsrc, unsigned short* __restrict__ C)
{
    __shared__ unsigned short As[128 * 40];   // 40-short stride: 80 B = 20 banks (2-way, free)
    __shared__ unsigned short Bs[128 * 40];
    const int m0 = blockIdx.x * 128;
    const int n0 = blockIdx.y * 128;
    const int tid = threadIdx.x;
    const int lane = tid & 63;
    const int quad = lane >> 4, lr = lane & 15;
    const int wid = tid >> 6;
    const int wm = wid & 1, wn = wid >> 1;
    const int srow = tid >> 1, scol = (tid & 1) * 16;
    const unsigned short* gA = A + (size_t)(m0 + srow) * 512 + scol;
    const unsigned short* gB = Bsrc + (size_t)(n0 + srow) * 512 + scol;

    f32x4v acc[4][4] = {};
    for (int k0 = 0; k0 < 512; k0 += 32) {
        us8v a0 = *(const us8v*)(gA + k0);
        us8v a1 = *(const us8v*)(gA + k0 + 8);
        us8v b0 = *(const us8v*)(gB + k0);
        us8v b1 = *(const us8v*)(gB + k0 + 8);
        __syncthreads();
        *(us8v*)&As[srow * 40 + scol]     = a0;
        *(us8v*)&As[srow * 40 + scol + 8] = a1;
        *(us8v*)&Bs[srow * 40 + scol]     = b0;
        *(us8v*)&Bs[srow * 40 + scol + 8] = b1;
        __syncthreads();
        bfrag af[4], bf_[4];
#pragma unroll
        for (int mi = 0; mi < 4; mi++)
            af[mi] = *(const bfrag*)&As[(wm * 64 + mi * 16 + lr) * 40 + quad * 8];
#pragma unroll
        for (int ni = 0; ni < 4; ni++)
            bf_[ni] = *(const bfrag*)&Bs[(wn * 64 + ni * 16 + lr) * 40 + quad * 8];
#pragma unroll
        for (int mi = 0; mi < 4; mi++)
#pragma unroll
            for (int ni = 0; ni < 4; ni++)
                acc[mi][ni] = __builtin_amdgcn_mfma_f32_16x16x32_bf16(
                    af[mi], bf_[ni], acc[mi][ni], 0, 0, 0);
    }
    // C/D layout: col = lane&15, row = quad*4 + reg  [m89/m91]
#pragma unroll
    for (int mi = 0; mi < 4; mi++)
#pragma unroll
        for (int ni = 0; ni < 4; ni++) {
            int col = n0 + wn * 64 + ni * 16 + lr;
#pragma unroll
            for (int r = 0; r < 4; r++) {
                int row = m0 + wm * 64 + mi * 16 + quad * 4 + r;
                C[(size_t)row * 512 + col] = f2bf(acc[mi][ni][r]);
            }
        }
}

// MFMA scores: wacc[b,s] += (1/512) * sum_t sigmoid((Y.X^T + rq_t + rk_s)/sqrt(H))
__global__ __launch_bounds__(256) void scores_k(const unsigned short* __restrict__ Y,
    const unsigned short* __restrict__ Xm, const float* __restrict__ rowq,
    const float* __restrict__ rowk, float* __restrict__ wacc)
{
    __shared__ unsigned short As[128 * 40];
    __shared__ unsigned short Bs[128 * 40];
    __shared__ float colsum[128];
    __shared__ float rq_s[128], rk_s[128];
    const int b  = blockIdx.z;
    const int m0 = blockIdx.x * 128;   // t tile
    const int n0 = blockIdx.y * 128;   // s tile
    const int tid = threadIdx.x;
    const int lane = tid & 63;
    const int quad = lane >> 4, lr = lane & 15;
    const int wid = tid >> 6;
    const int wm = wid & 1, wn = wid >> 1;
    const int srow = tid >> 1, scol = (tid & 1) * 16;
    const unsigned short* gA = Y  + (size_t)b * TTn * Hn + (size_t)(m0 + srow) * 512 + scol;
    const unsigned short* gB = Xm + (size_t)b * TTn * Hn + (size_t)(n0 + srow) * 512 + scol;

    if (tid < 128) {
        colsum[tid] = 0.f;
        rq_s[tid] = rowq[(size_t)b * TTn + m0 + tid];
        rk_s[tid] = rowk[(size_t)b * TTn + n0 + tid];
    }

    f32x4v acc[4][4] = {};
    for (int k0 = 0; k0 < 512; k0 += 32) {
        us8v a0 = *(const us8v*)(gA + k0);
        us8v a1 = *(const us8v*)(gA + k0 + 8);
        us8v b0 = *(const us8v*)(gB + k0);
        us8v b1 = *(const us8v*)(gB + k0 + 8);
        __syncthreads();
        *(us8v*)&As[srow * 40 + scol]     = a0;
        *(us8v*)&As[srow * 40 + scol + 8] = a1;
        *(us8v*)&Bs[srow * 40 + scol]     = b0;
        *(us8v*)&Bs[srow * 40 + scol + 8] = b1;
        __syncthreads();
        bfrag af[4], bf_[4];
#pragma unroll
        for (int mi = 0; mi < 4; mi++)
            af[mi] = *(const bfrag*)&As[(wm * 64 + mi * 16 + lr) * 40 + quad * 8];
#pragma unroll
        for (int ni = 0; ni < 4; ni++)
            bf_[ni] = *(const bfrag*)&Bs[(wn * 64 + ni * 16 + lr) * 40 + quad * 8];
#pragma unroll
        for (int mi = 0; mi < 4; mi++)
#pragma unroll
            for (int ni = 0; ni < 4; ni++)
                acc[mi][ni] = __builtin_amdgcn_mfma_f32_16x16x32_bf16(
                    af[mi], bf_[ni], acc[mi][ni], 0, 0, 0);
    }
    const float scl = 0.044194173824159216f;   // 512^-0.5
#pragma unroll
    for (int ni = 0; ni < 4; ni++) {
        float s_ln = 0.f;
        float rkv = rk_s[wn * 64 + ni * 16 + lr];
#pragma unroll
        for (int mi = 0; mi < 4; mi++) {
#pragma unroll
            for (int r = 0; r < 4; r++) {
                float rqv = rq_s[wm * 64 + mi * 16 + quad * 4 + r];
                float xv = (acc[mi][ni][r] + rqv + rkv) * scl;
                s_ln += 1.f / (1.f + __expf(-xv));
            }
        }
        atomicAdd(&colsum[wn * 64 + ni * 16 + lr], s_ln);
    }
    __syncthreads();
    if (tid < 128)
        atomicAdd(&wacc[(size_t)b * TTn + n0 + tid], colsum[tid] * (1.f / 512.f));
}

// rowq[r] = mem3[r,:].qb + c0 ; rowk[r] = mem3[r,:].kb   (mem3 bf16)
__global__ __launch_bounds__(256) void rows_k(const unsigned short* __restrict__ mem3b,
    const float* __restrict__ qb, const float* __restrict__ kb,
    const float* __restrict__ c0, float* __restrict__ rowq, float* __restrict__ rowk)
{
    const int wave = threadIdx.x >> 6;
    const int lane = threadIdx.x & 63;
    const int row = blockIdx.x * 4 + wave;
    const us8v xv8 = *(const us8v*)(mem3b + (size_t)row * 512 + lane * 8);
    float xr[8];
#pragma unroll
    for (int j = 0; j < 8; j++) xr[j] = bf2f(xv8[j]);
    const float4 q0 = *(const float4*)(qb + lane * 8);
    const float4 q1 = *(const float4*)(qb + lane * 8 + 4);
    const float4 k0 = *(const float4*)(kb + lane * 8);
    const float4 k1 = *(const float4*)(kb + lane * 8 + 4);
    float sq = xr[0]*q0.x + xr[1]*q0.y + xr[2]*q0.z + xr[3]*q0.w
             + xr[4]*q1.x + xr[5]*q1.y + xr[6]*q1.z + xr[7]*q1.w;
    float sk = xr[0]*k0.x + xr[1]*k0.y + xr[2]*k0.z + xr[3]*k0.w
             + xr[4]*k1.x + xr[5]*k1.y + xr[6]*k1.z + xr[7]*k1.w;
#pragma unroll
    for (int off = 32; off > 0; off >>= 1) {
        sq += __shfl_down(sq, off);
        sk += __shfl_down(sk, off);
    }
    if (lane == 0) {
        rowq[row] = sq + c0[0];
        rowk[row] = sk;
    }
}

// u[b,e] = sum_s wacc[b,s]*mem3[b,s,e];  W1[b] = sum_s wacc[b,s]
__global__ __launch_bounds__(256) void wsum_k(const float* __restrict__ wacc,
    const unsigned short* __restrict__ mem3b, float* __restrict__ u,
    float* __restrict__ W1)
{
    const int b = blockIdx.x;
    const int tid = threadIdx.x;
    __shared__ float ws_[512];
    __shared__ float red[256];
    ws_[tid] = wacc[(size_t)b * TTn + tid];
    ws_[tid + 256] = wacc[(size_t)b * TTn + tid + 256];
    __syncthreads();
    red[tid] = ws_[tid] + ws_[tid + 256];
    __syncthreads();
    for (int s = 128; s > 0; s >>= 1) {
        if (tid < s) red[tid] += red[tid + s];
        __syncthreads();
    }
    if (tid == 0) W1[b] = red[0];
    float a0 = 0.f, a1 = 0.f;
    const unsigned short* Xb = mem3b + (size_t)b * TTn * Hn;
    for (int s = 0; s < TTn; s++) {
        float w = ws_[s];
        a0 += w * bf2f(Xb[(size_t)s * Hn + tid]);
        a1 += w * bf2f(Xb[(size_t)s * Hn + tid + 256]);
    }
    u[(size_t)b * Hn + tid] = a0;
    u[(size_t)b * Hn + tid + 256] = a1;
}

// feat[b,d] = u[b,:].wv[d,:] + bv[d]*W1[b]
__global__ __launch_bounds__(256) void feat2_k(const float* __restrict__ u,
    const float* __restrict__ W1, const float* __restrict__ wv,
    const float* __restrict__ bv, float* __restrict__ feat)
{
    const int b = blockIdx.x;
    const int tid = threadIdx.x;
    __shared__ float us[512];
    us[tid] = u[(size_t)b * Hn + tid];
    us[tid + 256] = u[(size_t)b * Hn + tid + 256];
    __syncthreads();
    const float w1 = W1[b];
#pragma unroll
    for (int q = 0; q < 2; q++) {
        int d = tid + q * 256;
        float acc = bv[d] * w1;
        const float* wr = wv + (size_t)d * 512;
        for (int e = 0; e < 512; e += 4) {
            float4 w4 = *(const float4*)(wr + e);
            acc += us[e] * w4.x + us[e+1] * w4.y + us[e+2] * w4.z + us[e+3] * w4.w;
        }
        feat[(size_t)b * Hn + d] = acc;
    }
}

__global__ void bna_k(const float* __restrict__ feat, const float* __restrict__ g,
                      const float* __restrict__ bb, float* __restrict__ featn)
{
    int d = blockIdx.x * 256 + threadIdx.x;
    float s = 0.f, ss = 0.f;
    for (int b = 0; b < Bn; b++) { float v = feat[(size_t)b * Hn + d]; s += v; ss += v * v; }
    float m = s * (1.f / 128.f);
    float var = ss * (1.f / 128.f) - m * m;
    float sc = g[d] / sqrtf(var + EPSF);
    float sh = bb[d] - m * sc;
    for (int b = 0; b < Bn; b++) featn[(size_t)b * Hn + d] = feat[(size_t)b * Hn + d] * sc + sh;
}

__global__ __launch_bounds__(128) void head_k(const float* __restrict__ featn,
    const float* __restrict__ wh, const float* __restrict__ bh, float* __restrict__ out)
{
    const int b = blockIdx.x;
    __shared__ float f[512];
    const int tid = threadIdx.x;
    for (int i = tid; i < 512; i += 128) f[i] = featn[(size_t)b * Hn + i];
    __syncthreads();
    if (tid < HORn) {
        float accv = bh[tid];
        const float* wr = wh + (size_t)tid * Hn;
        for (int d = 0; d < 512; d++) accv += f[d] * wr[d];
        out[(size_t)b * HORn + tid] = accv;
    }
}

__global__ void dbg_k(float* out, float v) { out[0] = v; }

// ---------------------------------------------------------------------------
extern "C" void kernel_launch(void* const* d_in, const int* in_sizes, int n_in,
                              void* d_out, int out_size, void* d_ws, size_t ws_size,
                              hipStream_t stream)
{
    (void)in_sizes; (void)n_in;
    const float* x      = (const float*)d_in[0];
    const float* conv_w = (const float*)d_in[1];
    const float* conv_b = (const float*)d_in[2];
    const float* bn1_g  = (const float*)d_in[3];
    const float* bn1_b  = (const float*)d_in[4];
    const float* beta_e = (const float*)d_in[5];
    const float* bn2_g  = (const float*)d_in[6];
    const float* bn2_b  = (const float*)d_in[7];
    const float* beta2  = (const float*)d_in[8];
    const float* bn3_g  = (const float*)d_in[9];
    const float* bn3_b  = (const float*)d_in[10];
    const float* beta3  = (const float*)d_in[11];
    const float* wq     = (const float*)d_in[12];
    const float* bq     = (const float*)d_in[13];
    const float* wk     = (const float*)d_in[14];
    const float* bk     = (const float*)d_in[15];
    const float* wv     = (const float*)d_in[16];
    const float* bv     = (const float*)d_in[17];
    const float* bna_g  = (const float*)d_in[18];
    const float* bna_b  = (const float*)d_in[19];
    const float* wh     = (const float*)d_in[20];
    const float* bh     = (const float*)d_in[21];
    float* out = (float*)d_out;

    char* ws = (char*)d_ws;
    size_t off = 0;
    auto alloc = [&](size_t bytes) {
        char* p = ws + off;
        off += (bytes + 255) & ~(size_t)255;
        return p;
    };
    // Region 1: raw fp32 (134 MB); aliased by bf16 mem3 (67 MB) after lif1.
    float* raw          = (float*)alloc((size_t)TTn * Bn * Hn * 4);
    // Region 2: spk1 + s2 (67 MB); aliased by bf16 Y (67 MB) after lif3.
    unsigned char* spk1 = (unsigned char*)alloc((size_t)TTn * BH);
    unsigned char* s2   = (unsigned char*)alloc((size_t)TTn * BH);
    float* sums   = (float*)alloc(2 * On * 4);
    float* scale1 = (float*)alloc(On * 4);
    float* shift1 = (float*)alloc(On * 4);
    float* a2     = (float*)alloc((size_t)TTn * Hn * 4);
    float* z2     = (float*)alloc((size_t)TTn * Hn * 4);
    float* a3     = (float*)alloc((size_t)TTn * Hn * 4);
    float* z3     = (float*)alloc((size_t)TTn * Hn * 4);
    float* wacc   = (float*)alloc((size_t)Bn * TTn * 4);
    unsigned short* GT = (unsigned short*)alloc((size_t)Hn * Hn * 2);
    float* qb     = (float*)alloc(Hn * 4);
    float* kb     = (float*)alloc(Hn * 4);
    float* c0     = (float*)alloc(256);
    float* rowq   = (float*)alloc((size_t)Bn * TTn * 4);
    float* rowk   = (float*)alloc((size_t)Bn * TTn * 4);
    float* u      = (float*)alloc((size_t)Bn * Hn * 4);
    float* W1     = (float*)alloc(Bn * 4);
    float* feat   = (float*)alloc((size_t)Bn * Hn * 4);
    float* featn  = (float*)alloc((size_t)Bn * Hn * 4);
    unsigned short* mem3b = (unsigned short*)raw;   // raw dead after lif1
    unsigned short* Y     = (unsigned short*)spk1;  // spikes dead after lif3

    if (ws_size < off) {
        hipMemsetAsync(d_out, 0, (size_t)out_size * 4, stream);
        dbg_k<<<1, 1, 0, stream>>>(out, (float)ws_size);
        return;
    }

    hipMemsetAsync(sums, 0, 2 * On * 4, stream);
    hipMemsetAsync(wacc, 0, (size_t)Bn * TTn * 4, stream);

    conv_k<<<dim3(On / 64, Tn / 32, Bn), 256, 0, stream>>>(x, conv_w, conv_b, raw);
    bn1_stats_k<<<dim3(16, 4, 32), 256, 0, stream>>>(raw, sums);
    bn1_final_k<<<On / 256, 256, 0, stream>>>(sums, bn1_g, bn1_b, scale1, shift1);
    lif1_k<<<BH / 256, 256, 0, stream>>>(raw, scale1, shift1, beta_e, spk1);
    bnstep_k<<<TTn, 256, 0, stream>>>(spk1, bn2_g, bn2_b, a2, z2);
    lif2_k<<<BH / 256, 256, 0, stream>>>(spk1, a2, z2, beta2, s2);
    bnstep_k<<<TTn, 256, 0, stream>>>(s2, bn3_g, bn3_b, a3, z3);
    lif3_k<<<BH / 256, 256, 0, stream>>>(s2, a3, z3, beta3, mem3b);
    gemm_atb_k<<<dim3(4, 4), 256, 0, stream>>>(wk, wq, GT);   // GT = G^T (bf16)
    bias_prep_k<<<2, 256, 0, stream>>>(wq, wk, bq, bk, qb, kb, c0);
    ygemm_k<<<dim3((Bn * TTn) / 128, Hn / 128), 256, 0, stream>>>(mem3b, GT, Y);
    rows_k<<<(Bn * TTn) / 4, 256, 0, stream>>>(mem3b, qb, kb, c0, rowq, rowk);
    scores_k<<<dim3(TTn / 128, TTn / 128, Bn), 256, 0, stream>>>(Y, mem3b, rowq, rowk, wacc);
    wsum_k<<<Bn, 256, 0, stream>>>(wacc, mem3b, u, W1);
    feat2_k<<<Bn, 256, 0, stream>>>(u, W1, wv, bv, feat);
    bna_k<<<Hn / 256, 256, 0, stream>>>(feat, bna_g, bna_b, featn);
    head_k<<<Bn, 128, 0, stream>>>(featn, wh, bh, out);
}

// Round 6
// 636.542 us; speedup vs baseline: 2.1839x; 1.1608x over previous
//
#include <hip/hip_runtime.h>
#include <math.h>

#define EPSF 1e-5f

static constexpr int Bn   = 128;   // batch
static constexpr int Tn   = 128;   // conv time steps
static constexpr int Cn   = 32;    // conv in channels
static constexpr int On   = 2048;  // conv out channels = H*Ts
static constexpr int Hn   = 512;
static constexpr int TTn  = 512;   // total SNN steps = T*Ts
static constexpr int HORn = 96;
static constexpr int BH   = Bn * Hn;
static constexpr float THRf = 1.0f;

__device__ __forceinline__ float bf2f(unsigned short u) {
    union { unsigned int i; float f; } v; v.i = ((unsigned int)u) << 16; return v.f;
}
__device__ __forceinline__ unsigned short f2bf(float f) {
    union { float f; unsigned int i; } v; v.f = f;
    unsigned int r = v.i + 0x7fff + ((v.i >> 16) & 1);   // RNE
    return (unsigned short)(r >> 16);
}

using bfrag  = __attribute__((ext_vector_type(8))) short;   // 8 bf16 = 4 VGPRs
using f32x4v = __attribute__((ext_vector_type(4))) float;   // MFMA C/D
using us8v   = __attribute__((ext_vector_type(8))) unsigned short;

// ---------------------------------------------------------------------------
// im2col with split-bf16: Ph + Pl ≈ x to ~16 mantissa bits.
// P[(b*128+t)*96 + k*32 + c] = x[b, t+k-1, c] (zero-padded).
__global__ __launch_bounds__(256) void im2col_k(const float* __restrict__ x,
    unsigned short* __restrict__ Ph, unsigned short* __restrict__ Pl)
{
    int idx = blockIdx.x * 256 + threadIdx.x;        // 16384*96 total
    int row = idx / 96, kc = idx - row * 96;
    int k = kc >> 5, c = kc & 31;
    int t = row & 127, b = row >> 7;
    int tg = t + k - 1;
    float v = (tg >= 0 && tg < Tn) ? x[((size_t)b * Tn + tg) * Cn + c] : 0.f;
    unsigned short hi = f2bf(v);
    Ph[idx] = hi;
    Pl[idx] = f2bf(v - bf2f(hi));
}

// Wh/Wl[o*96 + k*32 + c] = split(conv_w[o*96 + c*3 + k]).
__global__ __launch_bounds__(256) void wprep_k(const float* __restrict__ wconv,
    unsigned short* __restrict__ Wh, unsigned short* __restrict__ Wl)
{
    int idx = blockIdx.x * 256 + threadIdx.x;        // 2048*96 total
    int o = idx / 96, kc = idx - o * 96;
    int k = kc >> 5, c = kc & 31;
    float v = wconv[(size_t)o * 96 + c * 3 + k];
    unsigned short hi = f2bf(v);
    Wh[idx] = hi;
    Wl[idx] = f2bf(v - bf2f(hi));
}

// Conv as NT MFMA GEMM with split-bf16 (hh + hl + lh passes), fp32 output.
// One block = one b (M=128 t) x 128 o.  K=96 = 3 ksteps.  No LDS: every MFMA
// fragment is a contiguous 16B global load (P/W row-major, row len 96).
__global__ __launch_bounds__(256) void conv_mfma_k(
    const unsigned short* __restrict__ Ph, const unsigned short* __restrict__ Pl,
    const unsigned short* __restrict__ Wh, const unsigned short* __restrict__ Wl,
    float* __restrict__ raw)
{
    const int b  = blockIdx.x;
    const int n0 = blockIdx.y * 128;
    const int tid = threadIdx.x;
    const int lane = tid & 63;
    const int quad = lane >> 4, lr = lane & 15;
    const int wid = tid >> 6, wm = wid & 1, wn = wid >> 1;

    f32x4v acc[4][4] = {};
#pragma unroll
    for (int ks = 0; ks < 3; ks++) {
        const int col = ks * 32 + quad * 8;
        bfrag ah[4], al[4], bh[4], bl[4];
#pragma unroll
        for (int mi = 0; mi < 4; mi++) {
            size_t roff = ((size_t)b * 128 + wm * 64 + mi * 16 + lr) * 96 + col;
            ah[mi] = *(const bfrag*)(Ph + roff);
            al[mi] = *(const bfrag*)(Pl + roff);
        }
#pragma unroll
        for (int ni = 0; ni < 4; ni++) {
            size_t roff = (size_t)(n0 + wn * 64 + ni * 16 + lr) * 96 + col;
            bh[ni] = *(const bfrag*)(Wh + roff);
            bl[ni] = *(const bfrag*)(Wl + roff);
        }
#pragma unroll
        for (int mi = 0; mi < 4; mi++)
#pragma unroll
            for (int ni = 0; ni < 4; ni++) {
                acc[mi][ni] = __builtin_amdgcn_mfma_f32_16x16x32_bf16(
                    ah[mi], bh[ni], acc[mi][ni], 0, 0, 0);
                acc[mi][ni] = __builtin_amdgcn_mfma_f32_16x16x32_bf16(
                    ah[mi], bl[ni], acc[mi][ni], 0, 0, 0);
                acc[mi][ni] = __builtin_amdgcn_mfma_f32_16x16x32_bf16(
                    al[mi], bh[ni], acc[mi][ni], 0, 0, 0);
            }
    }
    // C/D: col = lane&15 (o), row = quad*4 + reg (t)  [m89/m91]
#pragma unroll
    for (int mi = 0; mi < 4; mi++)
#pragma unroll
        for (int ni = 0; ni < 4; ni++) {
            int o = n0 + wn * 64 + ni * 16 + lr;
            int ts = o >> 9, hh = o & 511;
#pragma unroll
            for (int r = 0; r < 4; r++) {
                int t = wm * 64 + mi * 16 + quad * 4 + r;
                raw[((size_t)(t * 4 + ts) * Bn + b) * Hn + hh] = acc[mi][ni][r];
            }
        }
}

// ---------------------------------------------------------------------------
// BN1 stats over fp32 raw (no bias in raw): sum & sumsq per channel over (B,T).
__global__ __launch_bounds__(256) void bn1_stats_k(const float* __restrict__ raw,
                                                   float* __restrict__ sums)
{
    const int hb = blockIdx.x * 32;
    const int ts = blockIdx.y;
    const int tc = blockIdx.z;
    const int lane_h = threadIdx.x & 31;
    const int row = threadIdx.x >> 5;
    const int hh = hb + lane_h;
    float s = 0.f, ss = 0.f;
    for (int i = row; i < 512; i += 8) {
        int t = tc * 4 + (i >> 7);
        int b = i & 127;
        float v = raw[((size_t)(t * 4 + ts) * Bn + b) * Hn + hh];
        s += v; ss += v * v;
    }
    __shared__ float ls[8][33], lss[8][33];
    ls[row][lane_h] = s; lss[row][lane_h] = ss;
    __syncthreads();
    if (row == 0) {
#pragma unroll
        for (int r2 = 1; r2 < 8; r2++) { s += ls[r2][lane_h]; ss += lss[r2][lane_h]; }
        int o = ts * Hn + hh;
        atomicAdd(&sums[o], s);
        atomicAdd(&sums[On + o], ss);
    }
}

// Training-mode BN: conv bias cancels (shifts mean only, var unchanged).
// scale = g / sqrt(var);  shift = bb - m_nb*scale.
__global__ void bn1_final_k(const float* __restrict__ sums,
                            const float* __restrict__ g, const float* __restrict__ bb,
                            float* __restrict__ scale, float* __restrict__ shift)
{
    int o = blockIdx.x * 256 + threadIdx.x;
    float m = sums[o] * (1.f / 16384.f);
    float v = sums[On + o] * (1.f / 16384.f) - m * m;
    float sc = g[o] / sqrtf(v + EPSF);
    scale[o] = sc;
    shift[o] = bb[o] - m * sc;
}

// ---------------------------------------------------------------------------
__global__ __launch_bounds__(256) void lif1_k(const float* __restrict__ raw,
    const float* __restrict__ scale, const float* __restrict__ shift,
    const float* __restrict__ beta_in, unsigned char* __restrict__ spk)
{
    const int thr = blockIdx.x * 256 + threadIdx.x;
    const int hh = thr & 511;
    const float beta = fminf(fmaxf(beta_in[hh], 0.f), 0.99f);
    float sc[4], sh[4];
#pragma unroll
    for (int ts = 0; ts < 4; ts++) { sc[ts] = scale[ts * Hn + hh]; sh[ts] = shift[ts * Hn + hh]; }
    float mem = 0.f;
    for (int tt = 0; tt < TTn; tt += 8) {
        float cu[8];
#pragma unroll
        for (int u = 0; u < 8; u++) cu[u] = raw[(size_t)(tt + u) * BH + thr];
#pragma unroll
        for (int u = 0; u < 8; u++) {
            float cur = cu[u] * sc[u & 3] + sh[u & 3];
            float reset = mem > THRf ? 1.f : 0.f;
            mem = beta * mem + cur - reset;
            spk[(size_t)(tt + u) * BH + thr] = mem > THRf ? (unsigned char)1 : (unsigned char)0;
        }
    }
}

// ---------------------------------------------------------------------------
__global__ __launch_bounds__(256) void bnstep_k(const unsigned char* __restrict__ spk,
    const float* __restrict__ g, const float* __restrict__ bb,
    float* __restrict__ av, float* __restrict__ zv)
{
    const int tt = blockIdx.x;
    const int h0 = threadIdx.x * 2;
    int c0 = 0, c1 = 0;
    const unsigned char* base = spk + (size_t)tt * BH + h0;
#pragma unroll 8
    for (int b = 0; b < Bn; b++) {
        unsigned short v = *(const unsigned short*)(base + (size_t)b * Hn);
        c0 += (v & 0xff); c1 += (v >> 8);
    }
#pragma unroll
    for (int q = 0; q < 2; q++) {
        int hh = h0 + q;
        float p = (q ? c1 : c0) * (1.f / 128.f);
        float inv = 1.f / sqrtf(p - p * p + EPSF);
        float gi = g[hh] * inv;
        float zz = bb[hh] - p * gi;
        av[(size_t)tt * Hn + hh] = gi + zz;
        zv[(size_t)tt * Hn + hh] = zz;
    }
}

__global__ __launch_bounds__(256) void lif2_k(const unsigned char* __restrict__ sin_,
    const float* __restrict__ av, const float* __restrict__ zv,
    const float* __restrict__ beta_in, unsigned char* __restrict__ sout)
{
    const int thr = blockIdx.x * 256 + threadIdx.x;
    const int hh = thr & 511;
    const float beta = fminf(fmaxf(beta_in[hh], 0.f), 0.99f);
    float mem = 0.f;
    for (int tt = 0; tt < TTn; tt += 8) {
        float aa[8], zz[8]; unsigned char ss[8];
#pragma unroll
        for (int u = 0; u < 8; u++) {
            ss[u] = sin_[(size_t)(tt + u) * BH + thr];
            aa[u] = av[(size_t)(tt + u) * Hn + hh];
            zz[u] = zv[(size_t)(tt + u) * Hn + hh];
        }
#pragma unroll
        for (int u = 0; u < 8; u++) {
            float cur = ss[u] ? aa[u] : zz[u];
            float reset = mem > THRf ? 1.f : 0.f;
            mem = beta * mem + cur - reset;
            sout[(size_t)(tt + u) * BH + thr] = mem > THRf ? (unsigned char)1 : (unsigned char)0;
        }
    }
}

__global__ __launch_bounds__(256) void lif3_k(const unsigned char* __restrict__ sin_,
    const float* __restrict__ av, const float* __restrict__ zv,
    const float* __restrict__ beta_in, unsigned short* __restrict__ mem3b)
{
    const int thr = blockIdx.x * 256 + threadIdx.x;
    const int hh = thr & 511;
    const int b = thr >> 9;
    const float beta = fminf(fmaxf(beta_in[hh], 0.f), 0.99f);
    float mem = 0.f;
    for (int tt = 0; tt < TTn; tt += 8) {
        float aa[8], zz[8]; unsigned char ss[8];
#pragma unroll
        for (int u = 0; u < 8; u++) {
            ss[u] = sin_[(size_t)(tt + u) * BH + thr];
            aa[u] = av[(size_t)(tt + u) * Hn + hh];
            zz[u] = zv[(size_t)(tt + u) * Hn + hh];
        }
#pragma unroll
        for (int u = 0; u < 8; u++) {
            float cur = ss[u] ? aa[u] : zz[u];
            float reset = mem > THRf ? 1.f : 0.f;
            mem = beta * mem + cur - reset;
            mem3b[((size_t)b * TTn + (tt + u)) * Hn + hh] = f2bf(mem);
        }
    }
}

// ---------------------------------------------------------------------------
// GT[e,d] = sum_i wk[i,e] * wq[i,d] — bf16 output.
__global__ __launch_bounds__(256) void gemm_atb_k(const float* __restrict__ Aw,
    const float* __restrict__ Bw, unsigned short* __restrict__ C)
{
    __shared__ float As[8][132];
    __shared__ float Bs[8][132];
    const int m0 = blockIdx.x * 128;
    const int n0 = blockIdx.y * 128;
    const int tid = threadIdx.x;
    const int ir = tid >> 5, cl = (tid & 31) * 4;
    const float* Ap = Aw + (size_t)ir * 512 + m0 + cl;
    const float* Bp = Bw + (size_t)ir * 512 + n0 + cl;
    const int tm = tid & 15, tn = tid >> 4;
    float acc[8][8];
#pragma unroll
    for (int i = 0; i < 8; i++)
#pragma unroll
        for (int j = 0; j < 8; j++) acc[i][j] = 0.f;

    for (int i0 = 0; i0 < 512; i0 += 8) {
        const float4 avv = *(const float4*)(Ap + (size_t)i0 * 512);
        const float4 bvv = *(const float4*)(Bp + (size_t)i0 * 512);
        __syncthreads();
        *(float4*)&As[ir][cl] = avv;
        *(float4*)&Bs[ir][cl] = bvv;
        __syncthreads();
#pragma unroll
        for (int kk = 0; kk < 8; kk++) {
            float4 a0 = *(const float4*)&As[kk][tm * 8];
            float4 a1 = *(const float4*)&As[kk][tm * 8 + 4];
            float4 b0 = *(const float4*)&Bs[kk][tn * 8];
            float4 b1 = *(const float4*)&Bs[kk][tn * 8 + 4];
            float a_[8] = {a0.x, a0.y, a0.z, a0.w, a1.x, a1.y, a1.z, a1.w};
            float b_[8] = {b0.x, b0.y, b0.z, b0.w, b1.x, b1.y, b1.z, b1.w};
#pragma unroll
            for (int i = 0; i < 8; i++)
#pragma unroll
                for (int j = 0; j < 8; j++) acc[i][j] += a_[i] * b_[j];
        }
    }
#pragma unroll
    for (int i = 0; i < 8; i++) {
        size_t rowoff = (size_t)(m0 + tm * 8 + i) * 512 + n0 + tn * 8;
#pragma unroll
        for (int j = 0; j < 8; j++) C[rowoff + j] = f2bf(acc[i][j]);
    }
}

// qb[d] = sum_i wq[i,d]*bk[i]; kb[d] = sum_i wk[i,d]*bq[i]; c0 = bq.bk
__global__ __launch_bounds__(256) void bias_prep_k(const float* __restrict__ wq,
    const float* __restrict__ wk, const float* __restrict__ bq,
    const float* __restrict__ bk, float* __restrict__ qb, float* __restrict__ kb,
    float* __restrict__ c0)
{
    const int d = blockIdx.x * 256 + threadIdx.x;
    float sq = 0.f, sk = 0.f;
    for (int i = 0; i < 512; i++) {
        sq += wq[(size_t)i * 512 + d] * bk[i];
        sk += wk[(size_t)i * 512 + d] * bq[i];
    }
    qb[d] = sq; kb[d] = sk;
    if (blockIdx.x == 0) {
        __shared__ float red[256];
        float p = 0.f;
        for (int i = threadIdx.x; i < 512; i += 256) p += bq[i] * bk[i];
        red[threadIdx.x] = p;
        __syncthreads();
        for (int s = 128; s > 0; s >>= 1) {
            if (threadIdx.x < s) red[threadIdx.x] += red[threadIdx.x + s];
            __syncthreads();
        }
        if (threadIdx.x == 0) c0[0] = red[0];
    }
}

// ---------------------------------------------------------------------------
// MFMA NT GEMM: Y[r,e] = sum_d mem3b[r,d] * GT[e,d]; all bf16, fp32 acc.
__global__ __launch_bounds__(256) void ygemm_k(const unsigned short* __restrict__ A,
    const unsigned short* __restrict__ Bsrc, unsigned short* __restrict__ C)
{
    __shared__ unsigned short As[128 * 40];
    __shared__ unsigned short Bs[128 * 40];
    const int m0 = blockIdx.x * 128;
    const int n0 = blockIdx.y * 128;
    const int tid = threadIdx.x;
    const int lane = tid & 63;
    const int quad = lane >> 4, lr = lane & 15;
    const int wid = tid >> 6;
    const int wm = wid & 1, wn = wid >> 1;
    const int srow = tid >> 1, scol = (tid & 1) * 16;
    const unsigned short* gA = A + (size_t)(m0 + srow) * 512 + scol;
    const unsigned short* gB = Bsrc + (size_t)(n0 + srow) * 512 + scol;

    f32x4v acc[4][4] = {};
    for (int k0 = 0; k0 < 512; k0 += 32) {
        us8v a0 = *(const us8v*)(gA + k0);
        us8v a1 = *(const us8v*)(gA + k0 + 8);
        us8v b0 = *(const us8v*)(gB + k0);
        us8v b1 = *(const us8v*)(gB + k0 + 8);
        __syncthreads();
        *(us8v*)&As[srow * 40 + scol]     = a0;
        *(us8v*)&As[srow * 40 + scol + 8] = a1;
        *(us8v*)&Bs[srow * 40 + scol]     = b0;
        *(us8v*)&Bs[srow * 40 + scol + 8] = b1;
        __syncthreads();
        bfrag af[4], bf_[4];
#pragma unroll
        for (int mi = 0; mi < 4; mi++)
            af[mi] = *(const bfrag*)&As[(wm * 64 + mi * 16 + lr) * 40 + quad * 8];
#pragma unroll
        for (int ni = 0; ni < 4; ni++)
            bf_[ni] = *(const bfrag*)&Bs[(wn * 64 + ni * 16 + lr) * 40 + quad * 8];
#pragma unroll
        for (int mi = 0; mi < 4; mi++)
#pragma unroll
            for (int ni = 0; ni < 4; ni++)
                acc[mi][ni] = __builtin_amdgcn_mfma_f32_16x16x32_bf16(
                    af[mi], bf_[ni], acc[mi][ni], 0, 0, 0);
    }
#pragma unroll
    for (int mi = 0; mi < 4; mi++)
#pragma unroll
        for (int ni = 0; ni < 4; ni++) {
            int col = n0 + wn * 64 + ni * 16 + lr;
#pragma unroll
            for (int r = 0; r < 4; r++) {
                int row = m0 + wm * 64 + mi * 16 + quad * 4 + r;
                C[(size_t)row * 512 + col] = f2bf(acc[mi][ni][r]);
            }
        }
}

// MFMA scores: wacc[b,s] += (1/512) * sum_t sigmoid((Y.X^T + rq_t + rk_s)/sqrt(H))
__global__ __launch_bounds__(256) void scores_k(const unsigned short* __restrict__ Y,
    const unsigned short* __restrict__ Xm, const float* __restrict__ rowq,
    const float* __restrict__ rowk, float* __restrict__ wacc)
{
    __shared__ unsigned short As[128 * 40];
    __shared__ unsigned short Bs[128 * 40];
    __shared__ float colsum[128];
    __shared__ float rq_s[128], rk_s[128];
    const int b  = blockIdx.z;
    const int m0 = blockIdx.x * 128;   // t tile
    const int n0 = blockIdx.y * 128;   // s tile
    const int tid = threadIdx.x;
    const int lane = tid & 63;
    const int quad = lane >> 4, lr = lane & 15;
    const int wid = tid >> 6;
    const int wm = wid & 1, wn = wid >> 1;
    const int srow = tid >> 1, scol = (tid & 1) * 16;
    const unsigned short* gA = Y  + (size_t)b * TTn * Hn + (size_t)(m0 + srow) * 512 + scol;
    const unsigned short* gB = Xm + (size_t)b * TTn * Hn + (size_t)(n0 + srow) * 512 + scol;

    if (tid < 128) {
        colsum[tid] = 0.f;
        rq_s[tid] = rowq[(size_t)b * TTn + m0 + tid];
        rk_s[tid] = rowk[(size_t)b * TTn + n0 + tid];
    }

    f32x4v acc[4][4] = {};
    for (int k0 = 0; k0 < 512; k0 += 32) {
        us8v a0 = *(const us8v*)(gA + k0);
        us8v a1 = *(const us8v*)(gA + k0 + 8);
        us8v b0 = *(const us8v*)(gB + k0);
        us8v b1 = *(const us8v*)(gB + k0 + 8);
        __syncthreads();
        *(us8v*)&As[srow * 40 + scol]     = a0;
        *(us8v*)&As[srow * 40 + scol + 8] = a1;
        *(us8v*)&Bs[srow * 40 + scol]     = b0;
        *(us8v*)&Bs[srow * 40 + scol + 8] = b1;
        __syncthreads();
        bfrag af[4], bf_[4];
#pragma unroll
        for (int mi = 0; mi < 4; mi++)
            af[mi] = *(const bfrag*)&As[(wm * 64 + mi * 16 + lr) * 40 + quad * 8];
#pragma unroll
        for (int ni = 0; ni < 4; ni++)
            bf_[ni] = *(const bfrag*)&Bs[(wn * 64 + ni * 16 + lr) * 40 + quad * 8];
#pragma unroll
        for (int mi = 0; mi < 4; mi++)
#pragma unroll
            for (int ni = 0; ni < 4; ni++)
                acc[mi][ni] = __builtin_amdgcn_mfma_f32_16x16x32_bf16(
                    af[mi], bf_[ni], acc[mi][ni], 0, 0, 0);
    }
    const float scl = 0.044194173824159216f;
#pragma unroll
    for (int ni = 0; ni < 4; ni++) {
        float s_ln = 0.f;
        float rkv = rk_s[wn * 64 + ni * 16 + lr];
#pragma unroll
        for (int mi = 0; mi < 4; mi++) {
#pragma unroll
            for (int r = 0; r < 4; r++) {
                float rqv = rq_s[wm * 64 + mi * 16 + quad * 4 + r];
                float xv = (acc[mi][ni][r] + rqv + rkv) * scl;
                s_ln += 1.f / (1.f + __expf(-xv));
            }
        }
        atomicAdd(&colsum[wn * 64 + ni * 16 + lr], s_ln);
    }
    __syncthreads();
    if (tid < 128)
        atomicAdd(&wacc[(size_t)b * TTn + n0 + tid], colsum[tid] * (1.f / 512.f));
}

// rowq[r] = mem3[r,:].qb + c0 ; rowk[r] = mem3[r,:].kb   (mem3 bf16)
__global__ __launch_bounds__(256) void rows_k(const unsigned short* __restrict__ mem3b,
    const float* __restrict__ qb, const float* __restrict__ kb,
    const float* __restrict__ c0, float* __restrict__ rowq, float* __restrict__ rowk)
{
    const int wave = threadIdx.x >> 6;
    const int lane = threadIdx.x & 63;
    const int row = blockIdx.x * 4 + wave;
    const us8v xv8 = *(const us8v*)(mem3b + (size_t)row * 512 + lane * 8);
    float xr[8];
#pragma unroll
    for (int j = 0; j < 8; j++) xr[j] = bf2f(xv8[j]);
    const float4 q0 = *(const float4*)(qb + lane * 8);
    const float4 q1 = *(const float4*)(qb + lane * 8 + 4);
    const float4 k0 = *(const float4*)(kb + lane * 8);
    const float4 k1 = *(const float4*)(kb + lane * 8 + 4);
    float sq = xr[0]*q0.x + xr[1]*q0.y + xr[2]*q0.z + xr[3]*q0.w
             + xr[4]*q1.x + xr[5]*q1.y + xr[6]*q1.z + xr[7]*q1.w;
    float sk = xr[0]*k0.x + xr[1]*k0.y + xr[2]*k0.z + xr[3]*k0.w
             + xr[4]*k1.x + xr[5]*k1.y + xr[6]*k1.z + xr[7]*k1.w;
#pragma unroll
    for (int off = 32; off > 0; off >>= 1) {
        sq += __shfl_down(sq, off);
        sk += __shfl_down(sk, off);
    }
    if (lane == 0) {
        rowq[row] = sq + c0[0];
        rowk[row] = sk;
    }
}

// u[b,e] = sum_s wacc[b,s]*mem3[b,s,e];  W1[b] = sum_s wacc[b,s]
__global__ __launch_bounds__(256) void wsum_k(const float* __restrict__ wacc,
    const unsigned short* __restrict__ mem3b, float* __restrict__ u,
    float* __restrict__ W1)
{
    const int b = blockIdx.x;
    const int tid = threadIdx.x;
    __shared__ float ws_[512];
    __shared__ float red[256];
    ws_[tid] = wacc[(size_t)b * TTn + tid];
    ws_[tid + 256] = wacc[(size_t)b * TTn + tid + 256];
    __syncthreads();
    red[tid] = ws_[tid] + ws_[tid + 256];
    __syncthreads();
    for (int s = 128; s > 0; s >>= 1) {
        if (tid < s) red[tid] += red[tid + s];
        __syncthreads();
    }
    if (tid == 0) W1[b] = red[0];
    float a0 = 0.f, a1 = 0.f;
    const unsigned short* Xb = mem3b + (size_t)b * TTn * Hn;
    for (int s = 0; s < TTn; s++) {
        float w = ws_[s];
        a0 += w * bf2f(Xb[(size_t)s * Hn + tid]);
        a1 += w * bf2f(Xb[(size_t)s * Hn + tid + 256]);
    }
    u[(size_t)b * Hn + tid] = a0;
    u[(size_t)b * Hn + tid + 256] = a1;
}

// feat[b,d] = u[b,:].wv[d,:] + bv[d]*W1[b]
__global__ __launch_bounds__(256) void feat2_k(const float* __restrict__ u,
    const float* __restrict__ W1, const float* __restrict__ wv,
    const float* __restrict__ bv, float* __restrict__ feat)
{
    const int b = blockIdx.x;
    const int tid = threadIdx.x;
    __shared__ float us[512];
    us[tid] = u[(size_t)b * Hn + tid];
    us[tid + 256] = u[(size_t)b * Hn + tid + 256];
    __syncthreads();
    const float w1 = W1[b];
#pragma unroll
    for (int q = 0; q < 2; q++) {
        int d = tid + q * 256;
        float acc = bv[d] * w1;
        const float* wr = wv + (size_t)d * 512;
        for (int e = 0; e < 512; e += 4) {
            float4 w4 = *(const float4*)(wr + e);
            acc += us[e] * w4.x + us[e+1] * w4.y + us[e+2] * w4.z + us[e+3] * w4.w;
        }
        feat[(size_t)b * Hn + d] = acc;
    }
}

__global__ void bna_k(const float* __restrict__ feat, const float* __restrict__ g,
                      const float* __restrict__ bb, float* __restrict__ featn)
{
    int d = blockIdx.x * 256 + threadIdx.x;
    float s = 0.f, ss = 0.f;
    for (int b = 0; b < Bn; b++) { float v = feat[(size_t)b * Hn + d]; s += v; ss += v * v; }
    float m = s * (1.f / 128.f);
    float var = ss * (1.f / 128.f) - m * m;
    float sc = g[d] / sqrtf(var + EPSF);
    float sh = bb[d] - m * sc;
    for (int b = 0; b < Bn; b++) featn[(size_t)b * Hn + d] = feat[(size_t)b * Hn + d] * sc + sh;
}

__global__ __launch_bounds__(128) void head_k(const float* __restrict__ featn,
    const float* __restrict__ wh, const float* __restrict__ bh, float* __restrict__ out)
{
    const int b = blockIdx.x;
    __shared__ float f[512];
    const int tid = threadIdx.x;
    for (int i = tid; i < 512; i += 128) f[i] = featn[(size_t)b * Hn + i];
    __syncthreads();
    if (tid < HORn) {
        float accv = bh[tid];
        const float* wr = wh + (size_t)tid * Hn;
        for (int d = 0; d < 512; d++) accv += f[d] * wr[d];
        out[(size_t)b * HORn + tid] = accv;
    }
}

__global__ void dbg_k(float* out, float v) { out[0] = v; }

// ---------------------------------------------------------------------------
extern "C" void kernel_launch(void* const* d_in, const int* in_sizes, int n_in,
                              void* d_out, int out_size, void* d_ws, size_t ws_size,
                              hipStream_t stream)
{
    (void)in_sizes; (void)n_in;
    const float* x      = (const float*)d_in[0];
    const float* conv_w = (const float*)d_in[1];
    const float* bn1_g  = (const float*)d_in[3];
    const float* bn1_b  = (const float*)d_in[4];
    const float* beta_e = (const float*)d_in[5];
    const float* bn2_g  = (const float*)d_in[6];
    const float* bn2_b  = (const float*)d_in[7];
    const float* beta2  = (const float*)d_in[8];
    const float* bn3_g  = (const float*)d_in[9];
    const float* bn3_b  = (const float*)d_in[10];
    const float* beta3  = (const float*)d_in[11];
    const float* wq     = (const float*)d_in[12];
    const float* bq     = (const float*)d_in[13];
    const float* wk     = (const float*)d_in[14];
    const float* bk     = (const float*)d_in[15];
    const float* wv     = (const float*)d_in[16];
    const float* bv     = (const float*)d_in[17];
    const float* bna_g  = (const float*)d_in[18];
    const float* bna_b  = (const float*)d_in[19];
    const float* wh     = (const float*)d_in[20];
    const float* bh     = (const float*)d_in[21];
    float* out = (float*)d_out;

    char* ws = (char*)d_ws;
    size_t off = 0;
    auto alloc = [&](size_t bytes) {
        char* p = ws + off;
        off += (bytes + 255) & ~(size_t)255;
        return p;
    };
    // Region 1: fp32 raw (tt,b,h) 134 MB; aliased by bf16 mem3 (b,tt,h) after lif1.
    float* raw          = (float*)alloc((size_t)TTn * BH * 4);
    // Region 2: spk1 + s2 (67 MB); aliased by bf16 Y (67 MB) after lif3.
    unsigned char* spk1 = (unsigned char*)alloc((size_t)TTn * BH);
    unsigned char* s2   = (unsigned char*)alloc((size_t)TTn * BH);
    unsigned short* Ph = (unsigned short*)alloc((size_t)Bn * Tn * 96 * 2);
    unsigned short* Pl = (unsigned short*)alloc((size_t)Bn * Tn * 96 * 2);
    unsigned short* Wh = (unsigned short*)alloc((size_t)On * 96 * 2);
    unsigned short* Wl = (unsigned short*)alloc((size_t)On * 96 * 2);
    float* sums   = (float*)alloc(2 * On * 4);
    float* scale1 = (float*)alloc(On * 4);
    float* shift1 = (float*)alloc(On * 4);
    float* a2     = (float*)alloc((size_t)TTn * Hn * 4);
    float* z2     = (float*)alloc((size_t)TTn * Hn * 4);
    float* a3     = (float*)alloc((size_t)TTn * Hn * 4);
    float* z3     = (float*)alloc((size_t)TTn * Hn * 4);
    float* wacc   = (float*)alloc((size_t)Bn * TTn * 4);
    unsigned short* GT = (unsigned short*)alloc((size_t)Hn * Hn * 2);
    float* qb     = (float*)alloc(Hn * 4);
    float* kb     = (float*)alloc(Hn * 4);
    float* c0     = (float*)alloc(256);
    float* rowq   = (float*)alloc((size_t)Bn * TTn * 4);
    float* rowk   = (float*)alloc((size_t)Bn * TTn * 4);
    float* u      = (float*)alloc((size_t)Bn * Hn * 4);
    float* W1     = (float*)alloc(Bn * 4);
    float* feat   = (float*)alloc((size_t)Bn * Hn * 4);
    float* featn  = (float*)alloc((size_t)Bn * Hn * 4);
    unsigned short* mem3b = (unsigned short*)raw;   // raw dead after lif1
    unsigned short* Y     = (unsigned short*)spk1;  // spikes dead after lif3

    if (ws_size < off) {
        hipMemsetAsync(d_out, 0, (size_t)out_size * 4, stream);
        dbg_k<<<1, 1, 0, stream>>>(out, (float)ws_size);
        return;
    }

    hipMemsetAsync(sums, 0, 2 * On * 4, stream);
    hipMemsetAsync(wacc, 0, (size_t)Bn * TTn * 4, stream);

    im2col_k<<<(Bn * Tn * 96) / 256, 256, 0, stream>>>(x, Ph, Pl);
    wprep_k<<<(On * 96) / 256, 256, 0, stream>>>(conv_w, Wh, Wl);
    conv_mfma_k<<<dim3(Bn, On / 128), 256, 0, stream>>>(Ph, Pl, Wh, Wl, raw);
    bn1_stats_k<<<dim3(16, 4, 32), 256, 0, stream>>>(raw, sums);
    bn1_final_k<<<On / 256, 256, 0, stream>>>(sums, bn1_g, bn1_b, scale1, shift1);
    lif1_k<<<BH / 256, 256, 0, stream>>>(raw, scale1, shift1, beta_e, spk1);
    bnstep_k<<<TTn, 256, 0, stream>>>(spk1, bn2_g, bn2_b, a2, z2);
    lif2_k<<<BH / 256, 256, 0, stream>>>(spk1, a2, z2, beta2, s2);
    bnstep_k<<<TTn, 256, 0, stream>>>(s2, bn3_g, bn3_b, a3, z3);
    lif3_k<<<BH / 256, 256, 0, stream>>>(s2, a3, z3, beta3, mem3b);
    gemm_atb_k<<<dim3(4, 4), 256, 0, stream>>>(wk, wq, GT);   // GT = G^T (bf16)
    bias_prep_k<<<2, 256, 0, stream>>>(wq, wk, bq, bk, qb, kb, c0);
    ygemm_k<<<dim3((Bn * TTn) / 128, Hn / 128), 256, 0, stream>>>(mem3b, GT, Y);
    rows_k<<<(Bn * TTn) / 4, 256, 0, stream>>>(mem3b, qb, kb, c0, rowq, rowk);
    scores_k<<<dim3(TTn / 128, TTn / 128, Bn), 256, 0, stream>>>(Y, mem3b, rowq, rowk, wacc);
    wsum_k<<<Bn, 256, 0, stream>>>(wacc, mem3b, u, W1);
    feat2_k<<<Bn, 256, 0, stream>>>(u, W1, wv, bv, feat);
    bna_k<<<Hn / 256, 256, 0, stream>>>(feat, bna_g, bna_b, featn);
    head_k<<<Bn, 128, 0, stream>>>(featn, wh, bh, out);
}